// Round 9
// baseline (318.792 us; speedup 1.0000x reference)
//
#include <hip/hip_runtime.h>

// Problem constants: B=8, C=512, L=4096, Ci=256, K=L/2=2048
#define BATCH 8
#define CIN   512
#define LEN   4096
#define CI    256
#define KLEN  2048

typedef _Float16 half_t;
typedef _Float16 half2_t __attribute__((ext_vector_type(2)));
typedef _Float16 half4_t __attribute__((ext_vector_type(4)));
typedef _Float16 half8_t __attribute__((ext_vector_type(8)));
typedef float    floatx4 __attribute__((ext_vector_type(4)));

// async global->LDS 16B copy (wave-uniform LDS base + lane*16 pattern required)
__device__ __forceinline__ void async16(void* lds_dst, const void* g_src) {
    __builtin_amdgcn_global_load_lds(
        (const __attribute__((address_space(1))) unsigned int*)g_src,
        (__attribute__((address_space(3))) unsigned int*)lds_dst,
        16, 0, 0);
}

// ---------------------------------------------------------------------------
// Kernel A: convert+transpose x[b][c][l] f32 -> xhT[b][l][c] f16.
// 64x64 tiles through LDS. Grid (65, CIN/64, B): blockIdx.x==64 blocks do
// the weight conversion (former wconv_kernel) to save one dispatch.
// ---------------------------------------------------------------------------
__global__ __launch_bounds__(256) void xpose_kernel(
    const float* __restrict__ x, half_t* __restrict__ xhT,
    const float* __restrict__ tw, const float* __restrict__ pw,
    const float* __restrict__ gw, const float* __restrict__ wzw,
    half_t* __restrict__ Wh, half_t* __restrict__ wzh)
{
    if (blockIdx.x == 64) {
        // weight conversion: Wh[768][512] = {theta,phi,g}, wzh[512][256].
        int slice = blockIdx.y * 8 + blockIdx.z;
        size_t base0 = (size_t)slice * 8192 + threadIdx.x * 8;
        #pragma unroll
        for (int it = 0; it < 4; it++) {
            size_t base = base0 + (size_t)it * 2048;
            const float* src;
            half_t* dst;
            if (base < 768 * 512) {
                size_t o = base >> 9, c = base & 511;
                src = (o < 256 ? tw + o * 512
                               : (o < 512 ? pw + (o - 256) * 512
                                          : gw + (o - 512) * 512)) + c;
                dst = Wh + base;
            } else {
                size_t off = base - 768 * 512;
                src = wzw + off;
                dst = wzh + off;
            }
            float4 a = *(const float4*)src, b2 = *(const float4*)(src + 4);
            half8_t h = { (half_t)a.x, (half_t)a.y, (half_t)a.z, (half_t)a.w,
                          (half_t)b2.x, (half_t)b2.y, (half_t)b2.z, (half_t)b2.w };
            *(half8_t*)dst = h;
        }
        return;
    }

    __shared__ half_t tile[64][72];   // [l][c], 144B rows (16B-aligned)
    const int b = blockIdx.z, c0 = blockIdx.y * 64, l0 = blockIdx.x * 64;
    const int t = threadIdx.x;
    #pragma unroll
    for (int i = 0; i < 4; i++) {
        int fid = t + 256 * i;                 // 1024 float4 reads
        int c = fid >> 4, lb = (fid & 15) << 2;
        float4 v = *(const float4*)(x + ((size_t)b * CIN + c0 + c) * LEN + l0 + lb);
        tile[lb + 0][c] = (half_t)v.x;
        tile[lb + 1][c] = (half_t)v.y;
        tile[lb + 2][c] = (half_t)v.z;
        tile[lb + 3][c] = (half_t)v.w;
    }
    __syncthreads();
    #pragma unroll
    for (int i = 0; i < 2; i++) {
        int fid = t + 256 * i;                 // 512 half8 writes
        int l = fid >> 3, cb = (fid & 7) << 3;
        half8_t v = *(const half8_t*)&tile[l][cb];
        *(half8_t*)(xhT + ((size_t)b * LEN + l0 + l) * CIN + c0 + cb) = v;
    }
}

// ---------------------------------------------------------------------------
// Kernel 1: MFMA projection GEMM.  out[o,l] = sum_c W[o,c] xhT[l,c].
// Round-9: each block covers ONE projection (which=blockIdx.y: 0=theta,
// 1=phi, 2=g) and BOTH of its 128-o halves: the x-tile is staged ONCE and
// feeds 2x16 MFMAs (x re-fetch 6x -> 3x, ~100MB saved). acc[2][4][4] = 128
// AGPR + ~70 arch VGPR fits the 128/128 split under (256,2) (r5-r7 model).
// Grid (L/128, 3, B) = 768 blocks.
// ---------------------------------------------------------------------------
__global__ __launch_bounds__(256, 2) void projmm_kernel(
    const half_t* __restrict__ xhT, const half_t* __restrict__ Wh,
    const float* __restrict__ tb, const float* __restrict__ pb,
    const float* __restrict__ gb,
    half_t* __restrict__ thetaT, half_t* __restrict__ phiT,
    half_t* __restrict__ gH)
{
    __shared__ half_t wsm[256 * 32];   // W tile [o 0..255][c], 64B rows
    __shared__ half_t xsm[128 * 32];   // x tile [l][c], 64B rows

    const int b     = blockIdx.z;
    const int which = blockIdx.y;       // 0=theta, 1=phi, 2=g
    const int l0    = blockIdx.x * 128;
    const int t     = threadIdx.x;
    const int lane = t & 63, w = t >> 6;
    const int ln = lane & 15, quad = lane >> 4;
    const int wm = w >> 1, wn = w & 1;

    floatx4 acc[2][4][4];
    #pragma unroll
    for (int h = 0; h < 2; h++)
        #pragma unroll
        for (int mi = 0; mi < 4; mi++)
            #pragma unroll
            for (int nj = 0; nj < 4; nj++) acc[h][mi][nj] = (floatx4)(0.0f);

    const half_t* Wb = Wh + (size_t)which * 256 * 512;
    const half_t* xb = xhT + ((size_t)b * LEN + l0) * CIN;

    for (int k0 = 0; k0 < 512; k0 += 32) {
        __syncthreads();
        #pragma unroll
        for (int it = 0; it < 4; it++) {        // 256 W rows, 16KB
            int off = t * 16 + it * 4096;
            int row = off >> 6, c8 = (off >> 4) & 3;
            async16(&wsm[off >> 1], Wb + (size_t)row * 512 + k0 + c8 * 8);
        }
        #pragma unroll
        for (int it = 0; it < 2; it++) {        // 128 x rows, 8KB
            int off = t * 16 + it * 4096;
            int row = off >> 6, c8 = (off >> 4) & 3;
            async16(&xsm[off >> 1], xb + (size_t)row * CIN + k0 + c8 * 8);
        }
        __syncthreads();
        half8_t bf[4];
        #pragma unroll
        for (int nj = 0; nj < 4; nj++)
            bf[nj] = *(const half8_t*)&xsm[(wn * 64 + nj * 16 + ln) * 32 + quad * 8];
        #pragma unroll
        for (int h = 0; h < 2; h++) {
            half8_t af[4];
            #pragma unroll
            for (int mi = 0; mi < 4; mi++)
                af[mi] = *(const half8_t*)&wsm[(h * 128 + wm * 64 + mi * 16 + ln) * 32 + quad * 8];
            #pragma unroll
            for (int mi = 0; mi < 4; mi++)
                #pragma unroll
                for (int nj = 0; nj < 4; nj++)
                    acc[h][mi][nj] = __builtin_amdgcn_mfma_f32_16x16x32_f16(
                                         af[mi], bf[nj], acc[h][mi][nj], 0, 0, 0);
        }
    }

    const float* Bp = which == 0 ? tb : (which == 1 ? pb : gb);

    #pragma unroll
    for (int h = 0; h < 2; h++) {
        const int obase = h * 128;
        float bias[4][4];
        #pragma unroll
        for (int mi = 0; mi < 4; mi++)
            #pragma unroll
            for (int r = 0; r < 4; r++)
                bias[mi][r] = Bp[obase + wm * 64 + mi * 16 + quad * 4 + r];

        if (which == 0) {
            #pragma unroll
            for (int mi = 0; mi < 4; mi++) {
                int o = obase + wm * 64 + mi * 16 + quad * 4;
                #pragma unroll
                for (int nj = 0; nj < 4; nj++) {
                    int l = l0 + wn * 64 + nj * 16 + ln;
                    half4_t v = { (half_t)(acc[h][mi][nj][0] + bias[mi][0]),
                                  (half_t)(acc[h][mi][nj][1] + bias[mi][1]),
                                  (half_t)(acc[h][mi][nj][2] + bias[mi][2]),
                                  (half_t)(acc[h][mi][nj][3] + bias[mi][3]) };
                    *(half4_t*)(thetaT + ((size_t)b * LEN + l) * CI + o) = v;
                }
            }
        } else {
            #pragma unroll
            for (int mi = 0; mi < 4; mi++) {
                int o = obase + wm * 64 + mi * 16 + quad * 4;
                #pragma unroll
                for (int nj = 0; nj < 4; nj++) {
                    int l = l0 + wn * 64 + nj * 16 + ln;
                    float mx[4];
                    #pragma unroll
                    for (int r = 0; r < 4; r++) {
                        float other = __shfl_xor(acc[h][mi][nj][r], 1);
                        mx[r] = fmaxf(acc[h][mi][nj][r], other) + bias[mi][r];
                    }
                    if ((ln & 1) == 0) {
                        int kk = l >> 1;
                        if (which == 1) {
                            half4_t v = { (half_t)mx[0], (half_t)mx[1],
                                          (half_t)mx[2], (half_t)mx[3] };
                            *(half4_t*)(phiT + ((size_t)b * KLEN + kk) * CI + o) = v;
                        } else {
                            #pragma unroll
                            for (int r = 0; r < 4; r++)
                                gH[((size_t)b * CI + o + r) * KLEN + kk] = (half_t)mx[r];
                        }
                    }
                }
            }
        }
    }
}

// ---------------------------------------------------------------------------
// Kernel 2: MFMA flash attention — EXACT round-4 kernel (fingerprint:
// VGPR 112, bank-conflicts 0, occ ~21%, 93-101us clock-dependent).
// ---------------------------------------------------------------------------
__global__ __launch_bounds__(256, 2) void attn_kernel(
    const half_t* __restrict__ thetaT,   // [B][L][CI]
    const half_t* __restrict__ phiT,     // [B][KLEN][CI]
    const half_t* __restrict__ gH,       // [B][CI][KLEN]
    half_t* __restrict__ yhT)            // [B][LEN][CI]
{
    __shared__ half_t phi_s[64 * 256];   // 64 rows x 512B, swizzled + row-perm
    __shared__ half_t g_s[256 * 64];     // 256 rows x 128B, granule-swizzled

    const int b    = blockIdx.x;
    const int q0   = blockIdx.y * 64;
    const int t    = threadIdx.x;
    const int w    = t >> 6;
    const int lane = t & 63;
    const int ln   = lane & 15;
    const int quad = lane >> 4;
    const int qw   = q0 + w * 16;

    half8_t thf[8];
    {
        const half_t* thb = thetaT + ((size_t)b * LEN + qw + ln) * CI + quad * 8;
        #pragma unroll
        for (int ch = 0; ch < 8; ch++)
            thf[ch] = *(const half8_t*)(thb + ch * 32);
    }

    floatx4 O[16];
    #pragma unroll
    for (int i = 0; i < 16; i++) O[i] = (floatx4)(0.0f);
    float m_run = -3.0e38f;
    float l_run = 0.0f;

    const half_t* phib = phiT + (size_t)b * KLEN * CI;
    const half_t* gb   = gH   + (size_t)b * CI * KLEN;

    for (int kt = 0; kt < KLEN; kt += 64) {
        __syncthreads();
        #pragma unroll
        for (int it = 0; it < 8; it++) {
            int o   = t * 16 + it * 4096;
            int rho = o >> 9;
            int gsw = (o >> 4) & 31;
            int gsrc = gsw ^ (rho & 31);
            // row permutation: LDS row rho holds key(rho)
            int key = ((rho >> 4) & 1) * 32 + ((rho >> 2) & 3) * 8
                    + ((rho >> 5) & 1) * 4 + (rho & 3);
            async16(&phi_s[o >> 1],
                    phib + (size_t)(kt + key) * CI + gsrc * 8);
        }
        #pragma unroll
        for (int it = 0; it < 8; it++) {
            int o   = t * 16 + it * 4096;
            int row = o >> 7;
            int gsw = (o >> 4) & 7;
            int gsrc = gsw ^ (row & 7);
            async16(&g_s[o >> 1],
                    gb + (size_t)row * KLEN + kt + gsrc * 8);
        }
        __syncthreads();

        floatx4 S[4];
        #pragma unroll
        for (int k16 = 0; k16 < 4; k16++) S[k16] = (floatx4)(0.0f);
        #pragma unroll
        for (int k16 = 0; k16 < 4; k16++) {
            int row = k16 * 16 + ln;
            int rs  = row & 31;
            #pragma unroll
            for (int ch = 0; ch < 8; ch++) {
                int gr = (ch * 4 + quad) ^ rs;
                half8_t a = *(const half8_t*)&phi_s[(row << 8) + gr * 8];
                S[k16] = __builtin_amdgcn_mfma_f32_16x16x32_f16(
                             a, thf[ch], S[k16], 0, 0, 0);
            }
        }

        float tmax = S[0][0];
        #pragma unroll
        for (int k16 = 0; k16 < 4; k16++)
            #pragma unroll
            for (int r = 0; r < 4; r++) tmax = fmaxf(tmax, S[k16][r]);
        tmax = fmaxf(tmax, __shfl_xor(tmax, 16));
        tmax = fmaxf(tmax, __shfl_xor(tmax, 32));
        if (tmax > m_run + 8.0f) {           // wave-uniform deferred rescale
            float alpha = __expf(m_run - tmax);
            m_run = tmax;
            l_run *= alpha;
            #pragma unroll
            for (int i = 0; i < 16; i++) O[i] *= alpha;
        }

        // P2[kk] = B-fragment for 16x16x32 PV: halfs j=0..3 from S[kk],
        // j=4..7 from S[kk+2] (register concat; key(rho) makes this exact).
        half8_t P2[2];
        #pragma unroll
        for (int kk = 0; kk < 2; kk++) {
            float ps[8];
            #pragma unroll
            for (int j = 0; j < 8; j++) {
                int k16 = kk + ((j >> 2) << 1);
                ps[j] = __expf(S[k16][j & 3] - m_run);
                l_run += ps[j];
            }
            half8_t pv = { (half_t)ps[0], (half_t)ps[1], (half_t)ps[2], (half_t)ps[3],
                           (half_t)ps[4], (half_t)ps[5], (half_t)ps[6], (half_t)ps[7] };
            P2[kk] = pv;
        }

        // PV: one conflict-free b128 g read per MFMA.
        const int lnm = ln & 7;
        #pragma unroll
        for (int kk = 0; kk < 2; kk++) {
            int gchunk = (4 * kk + quad) ^ lnm;     // 16B-chunk within 128B row
            #pragma unroll
            for (int csub = 0; csub < 16; csub++) {
                int row = csub * 16 + ln;
                half8_t a = *(const half8_t*)&g_s[(row << 6) + gchunk * 8];
                O[csub] = __builtin_amdgcn_mfma_f32_16x16x32_f16(
                              a, P2[kk], O[csub], 0, 0, 0);
            }
        }
    }

    l_run += __shfl_xor(l_run, 16);
    l_run += __shfl_xor(l_run, 32);
    float inv = 1.0f / l_run;
    // write yhT[b][q][c]: per lane fixed q=qw+ln, 16 x half4 at c=csub*16+quad*4
    half_t* yb = yhT + ((size_t)b * LEN + qw + ln) * CI;
    #pragma unroll
    for (int csub = 0; csub < 16; csub++) {
        int c = csub * 16 + quad * 4;
        half4_t v = { (half_t)(O[csub][0] * inv), (half_t)(O[csub][1] * inv),
                      (half_t)(O[csub][2] * inv), (half_t)(O[csub][3] * inv) };
        *(half4_t*)(yb + c) = v;
    }
}

// ---------------------------------------------------------------------------
// Kernel 3: MFMA zgemm. z[o,l] = sum_c wzh[o,c] yhT[l,c] + wz_b, f16 out.
// Round-9: each block covers TWO 128-o halves (o0 = blockIdx.y*256): the
// y-tile (af) is staged once and feeds both; y re-fetch 4x -> 2x.
// acc[2][4][4] = 128 AGPR. Grid (L/128, 2, B) = 512 blocks.
// ---------------------------------------------------------------------------
__global__ __launch_bounds__(256, 2) void zmm_kernel(
    const half_t* __restrict__ yhT, const half_t* __restrict__ wzh,
    const float* __restrict__ wzb, half_t* __restrict__ zh,
    float* __restrict__ bns, float* __restrict__ bnq)
{
    __shared__ half_t ysm[128 * 32];   // y tile [l][c]
    __shared__ half_t wsm[256 * 32];   // W tile [o 0..255][c]

    const int b  = blockIdx.z;
    const int o0 = blockIdx.y * 256;
    const int l0 = blockIdx.x * 128;
    const int t  = threadIdx.x;
    const int lane = t & 63, w = t >> 6;
    const int ln = lane & 15, quad = lane >> 4;
    const int wm = w >> 1, wn = w & 1;

    floatx4 acc[2][4][4];
    #pragma unroll
    for (int h = 0; h < 2; h++)
        #pragma unroll
        for (int mi = 0; mi < 4; mi++)
            #pragma unroll
            for (int nj = 0; nj < 4; nj++) acc[h][mi][nj] = (floatx4)(0.0f);

    const half_t* yb = yhT + ((size_t)b * LEN + l0) * CI;
    const half_t* Wb = wzh + (size_t)o0 * CI;

    for (int k0 = 0; k0 < 256; k0 += 32) {
        __syncthreads();
        #pragma unroll
        for (int it = 0; it < 2; it++) {        // 128 y rows, 8KB
            int off = t * 16 + it * 4096;
            int row = off >> 6, c8 = (off >> 4) & 3;
            async16(&ysm[off >> 1], yb + (size_t)row * CI + k0 + c8 * 8);
        }
        #pragma unroll
        for (int it = 0; it < 4; it++) {        // 256 W rows, 16KB
            int off = t * 16 + it * 4096;
            int row = off >> 6, c8 = (off >> 4) & 3;
            async16(&wsm[off >> 1], Wb + (size_t)row * CI + k0 + c8 * 8);
        }
        __syncthreads();
        half8_t af[4];
        #pragma unroll
        for (int mi = 0; mi < 4; mi++)
            af[mi] = *(const half8_t*)&ysm[(wm * 64 + mi * 16 + ln) * 32 + quad * 8];
        #pragma unroll
        for (int h = 0; h < 2; h++) {
            half8_t bf[4];
            #pragma unroll
            for (int nj = 0; nj < 4; nj++)
                bf[nj] = *(const half8_t*)&wsm[(h * 128 + wn * 64 + nj * 16 + ln) * 32 + quad * 8];
            #pragma unroll
            for (int mi = 0; mi < 4; mi++)
                #pragma unroll
                for (int nj = 0; nj < 4; nj++)
                    acc[h][mi][nj] = __builtin_amdgcn_mfma_f32_16x16x32_f16(
                                         af[mi], bf[nj], acc[h][mi][nj], 0, 0, 0);
        }
    }

    // C: row = l = quad*4+r, col = o = ln
    #pragma unroll
    for (int h = 0; h < 2; h++) {
        float s[4] = {0, 0, 0, 0}, s2[4] = {0, 0, 0, 0};
        #pragma unroll
        for (int nj = 0; nj < 4; nj++) {
            int o = o0 + h * 128 + wn * 64 + nj * 16 + ln;
            float bo = wzb[o];
            #pragma unroll
            for (int mi = 0; mi < 4; mi++) {
                int l = l0 + wm * 64 + mi * 16 + quad * 4;
                float v0 = acc[h][mi][nj][0] + bo, v1 = acc[h][mi][nj][1] + bo;
                float v2 = acc[h][mi][nj][2] + bo, v3 = acc[h][mi][nj][3] + bo;
                half4_t hv = { (half_t)v0, (half_t)v1, (half_t)v2, (half_t)v3 };
                *(half4_t*)(zh + ((size_t)b * CIN + o) * LEN + l) = hv;
                s[nj]  += (v0 + v1) + (v2 + v3);
                s2[nj] += (v0 * v0 + v1 * v1) + (v2 * v2 + v3 * v3);
            }
        }
        #pragma unroll
        for (int nj = 0; nj < 4; nj++) {
            float sv = s[nj], qv = s2[nj];
            sv += __shfl_xor(sv, 16); sv += __shfl_xor(sv, 32);
            qv += __shfl_xor(qv, 16); qv += __shfl_xor(qv, 32);
            if (quad == 0) {
                int o = o0 + h * 128 + wn * 64 + nj * 16 + ln;
                atomicAdd(&bns[o], sv);
                atomicAdd(&bnq[o], qv);
            }
        }
    }
}

// ---------------------------------------------------------------------------
// Kernel 4: BN normalize (batch stats, biased var) + residual.
// Reads f16 z (half traffic), writes f32 out. 8 elements/thread.
// ---------------------------------------------------------------------------
__global__ __launch_bounds__(256) void bn_kernel(
    const half_t* __restrict__ zh, const float* __restrict__ x,
    float* __restrict__ out,
    const float* __restrict__ bns, const float* __restrict__ bnq,
    const float* __restrict__ gamma, const float* __restrict__ beta)
{
    size_t i8 = (size_t)blockIdx.x * 256 + threadIdx.x;
    size_t base = i8 << 3;
    int c = (int)((base >> 12) & (CIN - 1));
    const float invn = 1.0f / (BATCH * LEN);
    float mean = bns[c] * invn;
    float var  = bnq[c] * invn - mean * mean;
    float sc = gamma[c] * rsqrtf(var + 1e-5f);
    float sh = beta[c] - mean * sc;
    half8_t zv = *(const half8_t*)(zh + base);
    float4 x0 = *(const float4*)(x + base);
    float4 x1 = *(const float4*)(x + base + 4);
    float4 o0, o1;
    o0.x = (float)zv[0] * sc + sh + x0.x;
    o0.y = (float)zv[1] * sc + sh + x0.y;
    o0.z = (float)zv[2] * sc + sh + x0.z;
    o0.w = (float)zv[3] * sc + sh + x0.w;
    o1.x = (float)zv[4] * sc + sh + x1.x;
    o1.y = (float)zv[5] * sc + sh + x1.y;
    o1.z = (float)zv[6] * sc + sh + x1.z;
    o1.w = (float)zv[7] * sc + sh + x1.w;
    *(float4*)(out + base) = o0;
    *(float4*)(out + base + 4) = o1;
}

// ---------------------------------------------------------------------------
extern "C" void kernel_launch(void* const* d_in, const int* in_sizes, int n_in,
                              void* d_out, int out_size, void* d_ws, size_t ws_size,
                              hipStream_t stream)
{
    const float* x     = (const float*)d_in[0];
    const float* tw    = (const float*)d_in[1];
    const float* tb    = (const float*)d_in[2];
    const float* pw    = (const float*)d_in[3];
    const float* pb    = (const float*)d_in[4];
    const float* gw    = (const float*)d_in[5];
    const float* gb    = (const float*)d_in[6];
    const float* wzw   = (const float*)d_in[7];
    const float* wzb   = (const float*)d_in[8];
    const float* gamma = (const float*)d_in[9];
    const float* beta  = (const float*)d_in[10];

    float* out = (float*)d_out;

    half_t* xhT    = (half_t*)d_ws;                              // 33.6 MB
    half_t* thetaT = xhT    + (size_t)BATCH * LEN * CIN;         // 16.8 MB
    half_t* phiT   = thetaT + (size_t)BATCH * LEN * CI;          //  8.4 MB
    half_t* gH     = phiT   + (size_t)BATCH * KLEN * CI;         //  8.4 MB
    half_t* yhT    = gH     + (size_t)BATCH * CI * KLEN;         // 16.8 MB
    half_t* Wh     = yhT    + (size_t)BATCH * LEN * CI;          // 768 KB
    half_t* wzh    = Wh     + (size_t)768 * 512;                 // 256 KB
    float*  bns    = (float*)(wzh + (size_t)512 * 256);
    float*  bnq    = bns + CIN;
    // xhT region (33.6 MB) is dead after projmm -> reuse for f16 z:
    half_t* zh     = xhT;                                        // 33.6 MB

    hipMemsetAsync(bns, 0, 2 * CIN * sizeof(float), stream);

    xpose_kernel<<<dim3(65, CIN / 64, BATCH), 256, 0, stream>>>(
        x, xhT, tw, pw, gw, wzw, Wh, wzh);

    projmm_kernel<<<dim3(LEN / 128, 3, BATCH), 256, 0, stream>>>(
        xhT, Wh, tb, pb, gb, thetaT, phiT, gH);

    attn_kernel<<<dim3(BATCH, LEN / 64), 256, 0, stream>>>(
        thetaT, phiT, gH, yhT);

    zmm_kernel<<<dim3(LEN / 128, 2, BATCH), 256, 0, stream>>>(
        yhT, wzh, wzb, zh, bns, bnq);

    bn_kernel<<<(BATCH * CIN * LEN) / 8 / 256, 256, 0, stream>>>(
        zh, x, out, bns, bnq, gamma, beta);
}

// Round 10
// 303.666 us; speedup vs baseline: 1.0498x; 1.0498x over previous
//
#include <hip/hip_runtime.h>

// Problem constants: B=8, C=512, L=4096, Ci=256, K=L/2=2048
#define BATCH 8
#define CIN   512
#define LEN   4096
#define CI    256
#define KLEN  2048

typedef _Float16 half_t;
typedef _Float16 half2_t __attribute__((ext_vector_type(2)));
typedef _Float16 half4_t __attribute__((ext_vector_type(4)));
typedef _Float16 half8_t __attribute__((ext_vector_type(8)));
typedef float    floatx4 __attribute__((ext_vector_type(4)));

// async global->LDS 16B copy (wave-uniform LDS base + lane*16 pattern required)
__device__ __forceinline__ void async16(void* lds_dst, const void* g_src) {
    __builtin_amdgcn_global_load_lds(
        (const __attribute__((address_space(1))) unsigned int*)g_src,
        (__attribute__((address_space(3))) unsigned int*)lds_dst,
        16, 0, 0);
}

// ---------------------------------------------------------------------------
// Kernel A: convert+transpose x[b][c][l] f32 -> xhT[b][l][c] f16.
// 64x64 tiles through LDS. Grid (65, CIN/64, B): blockIdx.x==64 blocks do
// the weight conversion (former wconv_kernel); slice 0 also zeroes the BN
// partial-sum buffers (replaces the hipMemsetAsync dispatch; stream order
// guarantees completion before zmm's atomics, and it re-runs per iteration
// so re-poisoning semantics hold).
// ---------------------------------------------------------------------------
__global__ __launch_bounds__(256) void xpose_kernel(
    const float* __restrict__ x, half_t* __restrict__ xhT,
    const float* __restrict__ tw, const float* __restrict__ pw,
    const float* __restrict__ gw, const float* __restrict__ wzw,
    half_t* __restrict__ Wh, half_t* __restrict__ wzh,
    float* __restrict__ bns)
{
    if (blockIdx.x == 64) {
        int slice = blockIdx.y * 8 + blockIdx.z;
        if (slice == 0) {
            // zero bns[512] + bnq[512] (contiguous): 1024 floats, 4/thread
            *(float4*)(bns + threadIdx.x * 4) = make_float4(0.f, 0.f, 0.f, 0.f);
        }
        size_t base0 = (size_t)slice * 8192 + threadIdx.x * 8;
        #pragma unroll
        for (int it = 0; it < 4; it++) {
            size_t base = base0 + (size_t)it * 2048;
            const float* src;
            half_t* dst;
            if (base < 768 * 512) {
                size_t o = base >> 9, c = base & 511;
                src = (o < 256 ? tw + o * 512
                               : (o < 512 ? pw + (o - 256) * 512
                                          : gw + (o - 512) * 512)) + c;
                dst = Wh + base;
            } else {
                size_t off = base - 768 * 512;
                src = wzw + off;
                dst = wzh + off;
            }
            float4 a = *(const float4*)src, b2 = *(const float4*)(src + 4);
            half8_t h = { (half_t)a.x, (half_t)a.y, (half_t)a.z, (half_t)a.w,
                          (half_t)b2.x, (half_t)b2.y, (half_t)b2.z, (half_t)b2.w };
            *(half8_t*)dst = h;
        }
        return;
    }

    __shared__ half_t tile[64][72];   // [l][c], 144B rows (16B-aligned)
    const int b = blockIdx.z, c0 = blockIdx.y * 64, l0 = blockIdx.x * 64;
    const int t = threadIdx.x;
    #pragma unroll
    for (int i = 0; i < 4; i++) {
        int fid = t + 256 * i;                 // 1024 float4 reads
        int c = fid >> 4, lb = (fid & 15) << 2;
        float4 v = *(const float4*)(x + ((size_t)b * CIN + c0 + c) * LEN + l0 + lb);
        tile[lb + 0][c] = (half_t)v.x;
        tile[lb + 1][c] = (half_t)v.y;
        tile[lb + 2][c] = (half_t)v.z;
        tile[lb + 3][c] = (half_t)v.w;
    }
    __syncthreads();
    #pragma unroll
    for (int i = 0; i < 2; i++) {
        int fid = t + 256 * i;                 // 512 half8 writes
        int l = fid >> 3, cb = (fid & 7) << 3;
        half8_t v = *(const half8_t*)&tile[l][cb];
        *(half8_t*)(xhT + ((size_t)b * LEN + l0 + l) * CIN + c0 + cb) = v;
    }
}

// ---------------------------------------------------------------------------
// Kernel 1: MFMA projection GEMM (r8-exact; r9's 2-o-tile merge regressed:
// x re-reads were already same-XCD L2-hits since y-stride-32 blocks map to
// one XCD (32%8==0), so merging saved no HBM and cost LDS footprint + grid).
// out[o,l] = sum_c Wh[o,c] xhT[l,c], o=0..767; maxpool fused for phi/g.
// 128x128 tile, 4 waves, BK=32. Grid (L/128, 6, B).
// ---------------------------------------------------------------------------
__global__ __launch_bounds__(256, 2) void projmm_kernel(
    const half_t* __restrict__ xhT, const half_t* __restrict__ Wh,
    const float* __restrict__ tb, const float* __restrict__ pb,
    const float* __restrict__ gb,
    half_t* __restrict__ thetaT, half_t* __restrict__ phiT,
    half_t* __restrict__ gH)
{
    __shared__ half_t wsm[128 * 32];   // W tile [o][c], 64B rows
    __shared__ half_t xsm[128 * 32];   // x tile [l][c], 64B rows

    const int b  = blockIdx.z;
    const int o0 = blockIdx.y * 128;
    const int l0 = blockIdx.x * 128;
    const int t  = threadIdx.x;
    const int lane = t & 63, w = t >> 6;
    const int ln = lane & 15, quad = lane >> 4;
    const int wm = w >> 1, wn = w & 1;

    floatx4 acc[4][4];
    #pragma unroll
    for (int mi = 0; mi < 4; mi++)
        #pragma unroll
        for (int nj = 0; nj < 4; nj++) acc[mi][nj] = (floatx4)(0.0f);

    const half_t* Wb = Wh + (size_t)o0 * 512;
    const half_t* xb = xhT + ((size_t)b * LEN + l0) * CIN;

    for (int k0 = 0; k0 < 512; k0 += 32) {
        __syncthreads();
        #pragma unroll
        for (int it = 0; it < 2; it++) {
            int off = t * 16 + it * 4096;       // LDS byte offset
            int row = off >> 6, c8 = (off >> 4) & 3;
            async16(&wsm[off >> 1], Wb + (size_t)row * 512 + k0 + c8 * 8);
            async16(&xsm[off >> 1], xb + (size_t)row * CIN + k0 + c8 * 8);
        }
        __syncthreads();
        half8_t af[4], bf[4];
        #pragma unroll
        for (int mi = 0; mi < 4; mi++)
            af[mi] = *(const half8_t*)&wsm[(wm * 64 + mi * 16 + ln) * 32 + quad * 8];
        #pragma unroll
        for (int nj = 0; nj < 4; nj++)
            bf[nj] = *(const half8_t*)&xsm[(wn * 64 + nj * 16 + ln) * 32 + quad * 8];
        #pragma unroll
        for (int mi = 0; mi < 4; mi++)
            #pragma unroll
            for (int nj = 0; nj < 4; nj++)
                acc[mi][nj] = __builtin_amdgcn_mfma_f32_16x16x32_f16(
                                  af[mi], bf[nj], acc[mi][nj], 0, 0, 0);
    }

    const int which = o0 >> 8;          // 0=theta, 1=phi, 2=g
    const int obase = o0 & 255;
    const float* Bp = which == 0 ? tb : (which == 1 ? pb : gb);

    float bias[4][4];
    #pragma unroll
    for (int mi = 0; mi < 4; mi++)
        #pragma unroll
        for (int r = 0; r < 4; r++)
            bias[mi][r] = Bp[obase + wm * 64 + mi * 16 + quad * 4 + r];

    if (which == 0) {
        #pragma unroll
        for (int mi = 0; mi < 4; mi++) {
            int o = obase + wm * 64 + mi * 16 + quad * 4;
            #pragma unroll
            for (int nj = 0; nj < 4; nj++) {
                int l = l0 + wn * 64 + nj * 16 + ln;
                half4_t v = { (half_t)(acc[mi][nj][0] + bias[mi][0]),
                              (half_t)(acc[mi][nj][1] + bias[mi][1]),
                              (half_t)(acc[mi][nj][2] + bias[mi][2]),
                              (half_t)(acc[mi][nj][3] + bias[mi][3]) };
                *(half4_t*)(thetaT + ((size_t)b * LEN + l) * CI + o) = v;
            }
        }
    } else {
        #pragma unroll
        for (int mi = 0; mi < 4; mi++) {
            int o = obase + wm * 64 + mi * 16 + quad * 4;
            #pragma unroll
            for (int nj = 0; nj < 4; nj++) {
                int l = l0 + wn * 64 + nj * 16 + ln;
                float mx[4];
                #pragma unroll
                for (int r = 0; r < 4; r++) {
                    float other = __shfl_xor(acc[mi][nj][r], 1);
                    mx[r] = fmaxf(acc[mi][nj][r], other) + bias[mi][r];
                }
                if ((ln & 1) == 0) {
                    int kk = l >> 1;
                    if (which == 1) {
                        half4_t v = { (half_t)mx[0], (half_t)mx[1],
                                      (half_t)mx[2], (half_t)mx[3] };
                        *(half4_t*)(phiT + ((size_t)b * KLEN + kk) * CI + o) = v;
                    } else {
                        #pragma unroll
                        for (int r = 0; r < 4; r++)
                            gH[((size_t)b * CI + o + r) * KLEN + kk] = (half_t)mx[r];
                    }
                }
            }
        }
    }
}

// ---------------------------------------------------------------------------
// Kernel 2: MFMA flash attention — EXACT round-4 kernel (fingerprint:
// VGPR 112, bank-conflicts 0, occ ~21%, 93-101us clock-dependent).
// ---------------------------------------------------------------------------
__global__ __launch_bounds__(256, 2) void attn_kernel(
    const half_t* __restrict__ thetaT,   // [B][L][CI]
    const half_t* __restrict__ phiT,     // [B][KLEN][CI]
    const half_t* __restrict__ gH,       // [B][CI][KLEN]
    half_t* __restrict__ yhT)            // [B][LEN][CI]
{
    __shared__ half_t phi_s[64 * 256];   // 64 rows x 512B, swizzled + row-perm
    __shared__ half_t g_s[256 * 64];     // 256 rows x 128B, granule-swizzled

    const int b    = blockIdx.x;
    const int q0   = blockIdx.y * 64;
    const int t    = threadIdx.x;
    const int w    = t >> 6;
    const int lane = t & 63;
    const int ln   = lane & 15;
    const int quad = lane >> 4;
    const int qw   = q0 + w * 16;

    half8_t thf[8];
    {
        const half_t* thb = thetaT + ((size_t)b * LEN + qw + ln) * CI + quad * 8;
        #pragma unroll
        for (int ch = 0; ch < 8; ch++)
            thf[ch] = *(const half8_t*)(thb + ch * 32);
    }

    floatx4 O[16];
    #pragma unroll
    for (int i = 0; i < 16; i++) O[i] = (floatx4)(0.0f);
    float m_run = -3.0e38f;
    float l_run = 0.0f;

    const half_t* phib = phiT + (size_t)b * KLEN * CI;
    const half_t* gb   = gH   + (size_t)b * CI * KLEN;

    for (int kt = 0; kt < KLEN; kt += 64) {
        __syncthreads();
        #pragma unroll
        for (int it = 0; it < 8; it++) {
            int o   = t * 16 + it * 4096;
            int rho = o >> 9;
            int gsw = (o >> 4) & 31;
            int gsrc = gsw ^ (rho & 31);
            // row permutation: LDS row rho holds key(rho)
            int key = ((rho >> 4) & 1) * 32 + ((rho >> 2) & 3) * 8
                    + ((rho >> 5) & 1) * 4 + (rho & 3);
            async16(&phi_s[o >> 1],
                    phib + (size_t)(kt + key) * CI + gsrc * 8);
        }
        #pragma unroll
        for (int it = 0; it < 8; it++) {
            int o   = t * 16 + it * 4096;
            int row = o >> 7;
            int gsw = (o >> 4) & 7;
            int gsrc = gsw ^ (row & 7);
            async16(&g_s[o >> 1],
                    gb + (size_t)row * KLEN + kt + gsrc * 8);
        }
        __syncthreads();

        floatx4 S[4];
        #pragma unroll
        for (int k16 = 0; k16 < 4; k16++) S[k16] = (floatx4)(0.0f);
        #pragma unroll
        for (int k16 = 0; k16 < 4; k16++) {
            int row = k16 * 16 + ln;
            int rs  = row & 31;
            #pragma unroll
            for (int ch = 0; ch < 8; ch++) {
                int gr = (ch * 4 + quad) ^ rs;
                half8_t a = *(const half8_t*)&phi_s[(row << 8) + gr * 8];
                S[k16] = __builtin_amdgcn_mfma_f32_16x16x32_f16(
                             a, thf[ch], S[k16], 0, 0, 0);
            }
        }

        float tmax = S[0][0];
        #pragma unroll
        for (int k16 = 0; k16 < 4; k16++)
            #pragma unroll
            for (int r = 0; r < 4; r++) tmax = fmaxf(tmax, S[k16][r]);
        tmax = fmaxf(tmax, __shfl_xor(tmax, 16));
        tmax = fmaxf(tmax, __shfl_xor(tmax, 32));
        if (tmax > m_run + 8.0f) {           // wave-uniform deferred rescale
            float alpha = __expf(m_run - tmax);
            m_run = tmax;
            l_run *= alpha;
            #pragma unroll
            for (int i = 0; i < 16; i++) O[i] *= alpha;
        }

        // P2[kk] = B-fragment for 16x16x32 PV: halfs j=0..3 from S[kk],
        // j=4..7 from S[kk+2] (register concat; key(rho) makes this exact).
        half8_t P2[2];
        #pragma unroll
        for (int kk = 0; kk < 2; kk++) {
            float ps[8];
            #pragma unroll
            for (int j = 0; j < 8; j++) {
                int k16 = kk + ((j >> 2) << 1);
                ps[j] = __expf(S[k16][j & 3] - m_run);
                l_run += ps[j];
            }
            half8_t pv = { (half_t)ps[0], (half_t)ps[1], (half_t)ps[2], (half_t)ps[3],
                           (half_t)ps[4], (half_t)ps[5], (half_t)ps[6], (half_t)ps[7] };
            P2[kk] = pv;
        }

        // PV: one conflict-free b128 g read per MFMA.
        const int lnm = ln & 7;
        #pragma unroll
        for (int kk = 0; kk < 2; kk++) {
            int gchunk = (4 * kk + quad) ^ lnm;     // 16B-chunk within 128B row
            #pragma unroll
            for (int csub = 0; csub < 16; csub++) {
                int row = csub * 16 + ln;
                half8_t a = *(const half8_t*)&g_s[(row << 6) + gchunk * 8];
                O[csub] = __builtin_amdgcn_mfma_f32_16x16x32_f16(
                              a, P2[kk], O[csub], 0, 0, 0);
            }
        }
    }

    l_run += __shfl_xor(l_run, 16);
    l_run += __shfl_xor(l_run, 32);
    float inv = 1.0f / l_run;
    // write yhT[b][q][c]: per lane fixed q=qw+ln, 16 x half4 at c=csub*16+quad*4
    half_t* yb = yhT + ((size_t)b * LEN + qw + ln) * CI;
    #pragma unroll
    for (int csub = 0; csub < 16; csub++) {
        int c = csub * 16 + quad * 4;
        half4_t v = { (half_t)(O[csub][0] * inv), (half_t)(O[csub][1] * inv),
                      (half_t)(O[csub][2] * inv), (half_t)(O[csub][3] * inv) };
        *(half4_t*)(yb + c) = v;
    }
}

// ---------------------------------------------------------------------------
// Kernel 3: MFMA zgemm (r8-exact). z[o,l] = sum_c wzh[o,c] yhT[l,c] + wz_b,
// f16 out into workspace; BN partial sums in f32 from un-quantized acc.
// Grid (L/128, 4, B).
// ---------------------------------------------------------------------------
__global__ __launch_bounds__(256, 2) void zmm_kernel(
    const half_t* __restrict__ yhT, const half_t* __restrict__ wzh,
    const float* __restrict__ wzb, half_t* __restrict__ zh,
    float* __restrict__ bns, float* __restrict__ bnq)
{
    __shared__ half_t ysm[128 * 32];   // y tile [l][c]
    __shared__ half_t wsm[128 * 32];   // W tile [o][c]

    const int b  = blockIdx.z;
    const int o0 = blockIdx.y * 128;
    const int l0 = blockIdx.x * 128;
    const int t  = threadIdx.x;
    const int lane = t & 63, w = t >> 6;
    const int ln = lane & 15, quad = lane >> 4;
    const int wm = w >> 1, wn = w & 1;

    floatx4 acc[4][4];
    #pragma unroll
    for (int mi = 0; mi < 4; mi++)
        #pragma unroll
        for (int nj = 0; nj < 4; nj++) acc[mi][nj] = (floatx4)(0.0f);

    const half_t* yb = yhT + ((size_t)b * LEN + l0) * CI;
    const half_t* Wb = wzh + (size_t)o0 * CI;

    for (int k0 = 0; k0 < 256; k0 += 32) {
        __syncthreads();
        #pragma unroll
        for (int it = 0; it < 2; it++) {
            int off = t * 16 + it * 4096;
            int row = off >> 6, c8 = (off >> 4) & 3;
            async16(&ysm[off >> 1], yb + (size_t)row * CI + k0 + c8 * 8);
            async16(&wsm[off >> 1], Wb + (size_t)row * CI + k0 + c8 * 8);
        }
        __syncthreads();
        half8_t af[4], bf[4];
        #pragma unroll
        for (int mi = 0; mi < 4; mi++)
            af[mi] = *(const half8_t*)&ysm[(wm * 64 + mi * 16 + ln) * 32 + quad * 8];
        #pragma unroll
        for (int nj = 0; nj < 4; nj++)
            bf[nj] = *(const half8_t*)&wsm[(wn * 64 + nj * 16 + ln) * 32 + quad * 8];
        #pragma unroll
        for (int mi = 0; mi < 4; mi++)
            #pragma unroll
            for (int nj = 0; nj < 4; nj++)
                acc[mi][nj] = __builtin_amdgcn_mfma_f32_16x16x32_f16(
                                  af[mi], bf[nj], acc[mi][nj], 0, 0, 0);
    }

    // C: row = l = quad*4+r, col = o = ln
    float s[4] = {0, 0, 0, 0}, s2[4] = {0, 0, 0, 0};
    #pragma unroll
    for (int nj = 0; nj < 4; nj++) {
        int o = o0 + wn * 64 + nj * 16 + ln;
        float bo = wzb[o];
        #pragma unroll
        for (int mi = 0; mi < 4; mi++) {
            int l = l0 + wm * 64 + mi * 16 + quad * 4;
            float v0 = acc[mi][nj][0] + bo, v1 = acc[mi][nj][1] + bo;
            float v2 = acc[mi][nj][2] + bo, v3 = acc[mi][nj][3] + bo;
            half4_t hv = { (half_t)v0, (half_t)v1, (half_t)v2, (half_t)v3 };
            *(half4_t*)(zh + ((size_t)b * CIN + o) * LEN + l) = hv;
            s[nj]  += (v0 + v1) + (v2 + v3);
            s2[nj] += (v0 * v0 + v1 * v1) + (v2 * v2 + v3 * v3);
        }
    }
    #pragma unroll
    for (int nj = 0; nj < 4; nj++) {
        float sv = s[nj], qv = s2[nj];
        sv += __shfl_xor(sv, 16); sv += __shfl_xor(sv, 32);
        qv += __shfl_xor(qv, 16); qv += __shfl_xor(qv, 32);
        if (quad == 0) {
            int o = o0 + wn * 64 + nj * 16 + ln;
            atomicAdd(&bns[o], sv);
            atomicAdd(&bnq[o], qv);
        }
    }
}

// ---------------------------------------------------------------------------
// Kernel 4: BN normalize (batch stats, biased var) + residual.
// Reads f16 z (half traffic), writes f32 out. 8 elements/thread.
// ---------------------------------------------------------------------------
__global__ __launch_bounds__(256) void bn_kernel(
    const half_t* __restrict__ zh, const float* __restrict__ x,
    float* __restrict__ out,
    const float* __restrict__ bns, const float* __restrict__ bnq,
    const float* __restrict__ gamma, const float* __restrict__ beta)
{
    size_t i8 = (size_t)blockIdx.x * 256 + threadIdx.x;
    size_t base = i8 << 3;
    int c = (int)((base >> 12) & (CIN - 1));
    const float invn = 1.0f / (BATCH * LEN);
    float mean = bns[c] * invn;
    float var  = bnq[c] * invn - mean * mean;
    float sc = gamma[c] * rsqrtf(var + 1e-5f);
    float sh = beta[c] - mean * sc;
    half8_t zv = *(const half8_t*)(zh + base);
    float4 x0 = *(const float4*)(x + base);
    float4 x1 = *(const float4*)(x + base + 4);
    float4 o0, o1;
    o0.x = (float)zv[0] * sc + sh + x0.x;
    o0.y = (float)zv[1] * sc + sh + x0.y;
    o0.z = (float)zv[2] * sc + sh + x0.z;
    o0.w = (float)zv[3] * sc + sh + x0.w;
    o1.x = (float)zv[4] * sc + sh + x1.x;
    o1.y = (float)zv[5] * sc + sh + x1.y;
    o1.z = (float)zv[6] * sc + sh + x1.z;
    o1.w = (float)zv[7] * sc + sh + x1.w;
    *(float4*)(out + base) = o0;
    *(float4*)(out + base + 4) = o1;
}

// ---------------------------------------------------------------------------
extern "C" void kernel_launch(void* const* d_in, const int* in_sizes, int n_in,
                              void* d_out, int out_size, void* d_ws, size_t ws_size,
                              hipStream_t stream)
{
    const float* x     = (const float*)d_in[0];
    const float* tw    = (const float*)d_in[1];
    const float* tb    = (const float*)d_in[2];
    const float* pw    = (const float*)d_in[3];
    const float* pb    = (const float*)d_in[4];
    const float* gw    = (const float*)d_in[5];
    const float* gb    = (const float*)d_in[6];
    const float* wzw   = (const float*)d_in[7];
    const float* wzb   = (const float*)d_in[8];
    const float* gamma = (const float*)d_in[9];
    const float* beta  = (const float*)d_in[10];

    float* out = (float*)d_out;

    half_t* xhT    = (half_t*)d_ws;                              // 33.6 MB
    half_t* thetaT = xhT    + (size_t)BATCH * LEN * CIN;         // 16.8 MB
    half_t* phiT   = thetaT + (size_t)BATCH * LEN * CI;          //  8.4 MB
    half_t* gH     = phiT   + (size_t)BATCH * KLEN * CI;         //  8.4 MB
    half_t* yhT    = gH     + (size_t)BATCH * CI * KLEN;         // 16.8 MB
    half_t* Wh     = yhT    + (size_t)BATCH * LEN * CI;          // 768 KB
    half_t* wzh    = Wh     + (size_t)768 * 512;                 // 256 KB
    float*  bns    = (float*)(wzh + (size_t)512 * 256);
    float*  bnq    = bns + CIN;
    // xhT region (33.6 MB) is dead after projmm -> reuse for f16 z:
    half_t* zh     = xhT;                                        // 33.6 MB

    xpose_kernel<<<dim3(65, CIN / 64, BATCH), 256, 0, stream>>>(
        x, xhT, tw, pw, gw, wzw, Wh, wzh, bns);

    projmm_kernel<<<dim3(LEN / 128, 6, BATCH), 256, 0, stream>>>(
        xhT, Wh, tb, pb, gb, thetaT, phiT, gH);

    attn_kernel<<<dim3(BATCH, LEN / 64), 256, 0, stream>>>(
        thetaT, phiT, gH, yhT);

    zmm_kernel<<<dim3(LEN / 128, CIN / 128, BATCH), 256, 0, stream>>>(
        yhT, wzh, wzb, zh, bns, bnq);

    bn_kernel<<<(BATCH * CIN * LEN) / 8 / 256, 256, 0, stream>>>(
        zh, x, out, bns, bnq, gamma, beta);
}

// Round 11
// 300.186 us; speedup vs baseline: 1.0620x; 1.0116x over previous
//
#include <hip/hip_runtime.h>

// Problem constants: B=8, C=512, L=4096, Ci=256, K=L/2=2048
#define BATCH 8
#define CIN   512
#define LEN   4096
#define CI    256
#define KLEN  2048

typedef _Float16 half_t;
typedef _Float16 half2_t __attribute__((ext_vector_type(2)));
typedef _Float16 half4_t __attribute__((ext_vector_type(4)));
typedef _Float16 half8_t __attribute__((ext_vector_type(8)));
typedef float    floatx4 __attribute__((ext_vector_type(4)));

// async global->LDS 16B copy (wave-uniform LDS base + lane*16 pattern required)
__device__ __forceinline__ void async16(void* lds_dst, const void* g_src) {
    __builtin_amdgcn_global_load_lds(
        (const __attribute__((address_space(1))) unsigned int*)g_src,
        (__attribute__((address_space(3))) unsigned int*)lds_dst,
        16, 0, 0);
}

// ---------------------------------------------------------------------------
// Kernel A: convert+transpose x[b][c][l] f32 -> xhT[b][l][c] f16.
// 64x64 tiles through LDS. Grid (65, CIN/64, B): blockIdx.x==64 blocks do
// the weight conversion; slice 0 also zeroes the BN partial-sum buffers.
// ---------------------------------------------------------------------------
__global__ __launch_bounds__(256) void xpose_kernel(
    const float* __restrict__ x, half_t* __restrict__ xhT,
    const float* __restrict__ tw, const float* __restrict__ pw,
    const float* __restrict__ gw, const float* __restrict__ wzw,
    half_t* __restrict__ Wh, half_t* __restrict__ wzh,
    float* __restrict__ bns)
{
    if (blockIdx.x == 64) {
        int slice = blockIdx.y * 8 + blockIdx.z;
        if (slice == 0) {
            // zero bns[512] + bnq[512] (contiguous): 1024 floats, 4/thread
            *(float4*)(bns + threadIdx.x * 4) = make_float4(0.f, 0.f, 0.f, 0.f);
        }
        size_t base0 = (size_t)slice * 8192 + threadIdx.x * 8;
        #pragma unroll
        for (int it = 0; it < 4; it++) {
            size_t base = base0 + (size_t)it * 2048;
            const float* src;
            half_t* dst;
            if (base < 768 * 512) {
                size_t o = base >> 9, c = base & 511;
                src = (o < 256 ? tw + o * 512
                               : (o < 512 ? pw + (o - 256) * 512
                                          : gw + (o - 512) * 512)) + c;
                dst = Wh + base;
            } else {
                size_t off = base - 768 * 512;
                src = wzw + off;
                dst = wzh + off;
            }
            float4 a = *(const float4*)src, b2 = *(const float4*)(src + 4);
            half8_t h = { (half_t)a.x, (half_t)a.y, (half_t)a.z, (half_t)a.w,
                          (half_t)b2.x, (half_t)b2.y, (half_t)b2.z, (half_t)b2.w };
            *(half8_t*)dst = h;
        }
        return;
    }

    __shared__ half_t tile[64][72];   // [l][c], 144B rows (16B-aligned)
    const int b = blockIdx.z, c0 = blockIdx.y * 64, l0 = blockIdx.x * 64;
    const int t = threadIdx.x;
    #pragma unroll
    for (int i = 0; i < 4; i++) {
        int fid = t + 256 * i;                 // 1024 float4 reads
        int c = fid >> 4, lb = (fid & 15) << 2;
        float4 v = *(const float4*)(x + ((size_t)b * CIN + c0 + c) * LEN + l0 + lb);
        tile[lb + 0][c] = (half_t)v.x;
        tile[lb + 1][c] = (half_t)v.y;
        tile[lb + 2][c] = (half_t)v.z;
        tile[lb + 3][c] = (half_t)v.w;
    }
    __syncthreads();
    #pragma unroll
    for (int i = 0; i < 2; i++) {
        int fid = t + 256 * i;                 // 512 half8 writes
        int l = fid >> 3, cb = (fid & 7) << 3;
        half8_t v = *(const half8_t*)&tile[l][cb];
        *(half8_t*)(xhT + ((size_t)b * LEN + l0 + l) * CIN + c0 + cb) = v;
    }
}

// ---------------------------------------------------------------------------
// Kernel 1: MFMA projection GEMM. out[o,l] = sum_c Wh[o,c] xhT[l,c], o=0..767;
// maxpool fused for phi/g. 128x128 tile, 4 waves, BK=32. Grid (L/128, 6, B).
// Round-11: granule-swizzled LDS (g = quad ^ ((row>>1)&3)). The linear 64B-row
// layout had a 4-way bank conflict on every af/bf b128 read (8-lane phase:
// addr stride 64B -> banks {0,16} only), making the conflicted LDS pipe the
// k-loop critical path (~152cy vs MFMA's ~77cy). Swizzle spreads each phase
// across banks {0,4,..,28} exactly once (enumerated). Staging keeps LDS dest
// linear and permutes the global source column by the same involution.
// ---------------------------------------------------------------------------
__global__ __launch_bounds__(256, 2) void projmm_kernel(
    const half_t* __restrict__ xhT, const half_t* __restrict__ Wh,
    const float* __restrict__ tb, const float* __restrict__ pb,
    const float* __restrict__ gb,
    half_t* __restrict__ thetaT, half_t* __restrict__ phiT,
    half_t* __restrict__ gH)
{
    __shared__ half_t wsm[128 * 32];   // W tile [o][c], 64B rows, swizzled
    __shared__ half_t xsm[128 * 32];   // x tile [l][c], 64B rows, swizzled

    const int b  = blockIdx.z;
    const int o0 = blockIdx.y * 128;
    const int l0 = blockIdx.x * 128;
    const int t  = threadIdx.x;
    const int lane = t & 63, w = t >> 6;
    const int ln = lane & 15, quad = lane >> 4;
    const int wm = w >> 1, wn = w & 1;
    const int gsw = quad ^ ((ln >> 1) & 3);    // read-side swizzled granule

    floatx4 acc[4][4];
    #pragma unroll
    for (int mi = 0; mi < 4; mi++)
        #pragma unroll
        for (int nj = 0; nj < 4; nj++) acc[mi][nj] = (floatx4)(0.0f);

    const half_t* Wb = Wh + (size_t)o0 * 512;
    const half_t* xb = xhT + ((size_t)b * LEN + l0) * CIN;

    for (int k0 = 0; k0 < 512; k0 += 32) {
        __syncthreads();
        #pragma unroll
        for (int it = 0; it < 2; it++) {
            int off = t * 16 + it * 4096;       // LDS byte offset
            int row = off >> 6;
            int c8s = ((off >> 4) & 3) ^ ((row >> 1) & 3);   // swizzled src col
            async16(&wsm[off >> 1], Wb + (size_t)row * 512 + k0 + c8s * 8);
            async16(&xsm[off >> 1], xb + (size_t)row * CIN + k0 + c8s * 8);
        }
        __syncthreads();
        half8_t af[4], bf[4];
        #pragma unroll
        for (int mi = 0; mi < 4; mi++)
            af[mi] = *(const half8_t*)&wsm[(wm * 64 + mi * 16 + ln) * 32 + gsw * 8];
        #pragma unroll
        for (int nj = 0; nj < 4; nj++)
            bf[nj] = *(const half8_t*)&xsm[(wn * 64 + nj * 16 + ln) * 32 + gsw * 8];
        #pragma unroll
        for (int mi = 0; mi < 4; mi++)
            #pragma unroll
            for (int nj = 0; nj < 4; nj++)
                acc[mi][nj] = __builtin_amdgcn_mfma_f32_16x16x32_f16(
                                  af[mi], bf[nj], acc[mi][nj], 0, 0, 0);
    }

    const int which = o0 >> 8;          // 0=theta, 1=phi, 2=g
    const int obase = o0 & 255;
    const float* Bp = which == 0 ? tb : (which == 1 ? pb : gb);

    float bias[4][4];
    #pragma unroll
    for (int mi = 0; mi < 4; mi++)
        #pragma unroll
        for (int r = 0; r < 4; r++)
            bias[mi][r] = Bp[obase + wm * 64 + mi * 16 + quad * 4 + r];

    if (which == 0) {
        #pragma unroll
        for (int mi = 0; mi < 4; mi++) {
            int o = obase + wm * 64 + mi * 16 + quad * 4;
            #pragma unroll
            for (int nj = 0; nj < 4; nj++) {
                int l = l0 + wn * 64 + nj * 16 + ln;
                half4_t v = { (half_t)(acc[mi][nj][0] + bias[mi][0]),
                              (half_t)(acc[mi][nj][1] + bias[mi][1]),
                              (half_t)(acc[mi][nj][2] + bias[mi][2]),
                              (half_t)(acc[mi][nj][3] + bias[mi][3]) };
                *(half4_t*)(thetaT + ((size_t)b * LEN + l) * CI + o) = v;
            }
        }
    } else {
        #pragma unroll
        for (int mi = 0; mi < 4; mi++) {
            int o = obase + wm * 64 + mi * 16 + quad * 4;
            #pragma unroll
            for (int nj = 0; nj < 4; nj++) {
                int l = l0 + wn * 64 + nj * 16 + ln;
                float mx[4];
                #pragma unroll
                for (int r = 0; r < 4; r++) {
                    float other = __shfl_xor(acc[mi][nj][r], 1);
                    mx[r] = fmaxf(acc[mi][nj][r], other) + bias[mi][r];
                }
                if ((ln & 1) == 0) {
                    int kk = l >> 1;
                    if (which == 1) {
                        half4_t v = { (half_t)mx[0], (half_t)mx[1],
                                      (half_t)mx[2], (half_t)mx[3] };
                        *(half4_t*)(phiT + ((size_t)b * KLEN + kk) * CI + o) = v;
                    } else {
                        #pragma unroll
                        for (int r = 0; r < 4; r++)
                            gH[((size_t)b * CI + o + r) * KLEN + kk] = (half_t)mx[r];
                    }
                }
            }
        }
    }
}

// ---------------------------------------------------------------------------
// Kernel 2: MFMA flash attention — EXACT round-4 kernel (fingerprint:
// VGPR 112, bank-conflicts 0, occ ~21%, 93-101us clock-dependent).
// ---------------------------------------------------------------------------
__global__ __launch_bounds__(256, 2) void attn_kernel(
    const half_t* __restrict__ thetaT,   // [B][L][CI]
    const half_t* __restrict__ phiT,     // [B][KLEN][CI]
    const half_t* __restrict__ gH,       // [B][CI][KLEN]
    half_t* __restrict__ yhT)            // [B][LEN][CI]
{
    __shared__ half_t phi_s[64 * 256];   // 64 rows x 512B, swizzled + row-perm
    __shared__ half_t g_s[256 * 64];     // 256 rows x 128B, granule-swizzled

    const int b    = blockIdx.x;
    const int q0   = blockIdx.y * 64;
    const int t    = threadIdx.x;
    const int w    = t >> 6;
    const int lane = t & 63;
    const int ln   = lane & 15;
    const int quad = lane >> 4;
    const int qw   = q0 + w * 16;

    half8_t thf[8];
    {
        const half_t* thb = thetaT + ((size_t)b * LEN + qw + ln) * CI + quad * 8;
        #pragma unroll
        for (int ch = 0; ch < 8; ch++)
            thf[ch] = *(const half8_t*)(thb + ch * 32);
    }

    floatx4 O[16];
    #pragma unroll
    for (int i = 0; i < 16; i++) O[i] = (floatx4)(0.0f);
    float m_run = -3.0e38f;
    float l_run = 0.0f;

    const half_t* phib = phiT + (size_t)b * KLEN * CI;
    const half_t* gb   = gH   + (size_t)b * CI * KLEN;

    for (int kt = 0; kt < KLEN; kt += 64) {
        __syncthreads();
        #pragma unroll
        for (int it = 0; it < 8; it++) {
            int o   = t * 16 + it * 4096;
            int rho = o >> 9;
            int gsw = (o >> 4) & 31;
            int gsrc = gsw ^ (rho & 31);
            // row permutation: LDS row rho holds key(rho)
            int key = ((rho >> 4) & 1) * 32 + ((rho >> 2) & 3) * 8
                    + ((rho >> 5) & 1) * 4 + (rho & 3);
            async16(&phi_s[o >> 1],
                    phib + (size_t)(kt + key) * CI + gsrc * 8);
        }
        #pragma unroll
        for (int it = 0; it < 8; it++) {
            int o   = t * 16 + it * 4096;
            int row = o >> 7;
            int gsw = (o >> 4) & 7;
            int gsrc = gsw ^ (row & 7);
            async16(&g_s[o >> 1],
                    gb + (size_t)row * KLEN + kt + gsrc * 8);
        }
        __syncthreads();

        floatx4 S[4];
        #pragma unroll
        for (int k16 = 0; k16 < 4; k16++) S[k16] = (floatx4)(0.0f);
        #pragma unroll
        for (int k16 = 0; k16 < 4; k16++) {
            int row = k16 * 16 + ln;
            int rs  = row & 31;
            #pragma unroll
            for (int ch = 0; ch < 8; ch++) {
                int gr = (ch * 4 + quad) ^ rs;
                half8_t a = *(const half8_t*)&phi_s[(row << 8) + gr * 8];
                S[k16] = __builtin_amdgcn_mfma_f32_16x16x32_f16(
                             a, thf[ch], S[k16], 0, 0, 0);
            }
        }

        float tmax = S[0][0];
        #pragma unroll
        for (int k16 = 0; k16 < 4; k16++)
            #pragma unroll
            for (int r = 0; r < 4; r++) tmax = fmaxf(tmax, S[k16][r]);
        tmax = fmaxf(tmax, __shfl_xor(tmax, 16));
        tmax = fmaxf(tmax, __shfl_xor(tmax, 32));
        if (tmax > m_run + 8.0f) {           // wave-uniform deferred rescale
            float alpha = __expf(m_run - tmax);
            m_run = tmax;
            l_run *= alpha;
            #pragma unroll
            for (int i = 0; i < 16; i++) O[i] *= alpha;
        }

        // P2[kk] = B-fragment for 16x16x32 PV: halfs j=0..3 from S[kk],
        // j=4..7 from S[kk+2] (register concat; key(rho) makes this exact).
        half8_t P2[2];
        #pragma unroll
        for (int kk = 0; kk < 2; kk++) {
            float ps[8];
            #pragma unroll
            for (int j = 0; j < 8; j++) {
                int k16 = kk + ((j >> 2) << 1);
                ps[j] = __expf(S[k16][j & 3] - m_run);
                l_run += ps[j];
            }
            half8_t pv = { (half_t)ps[0], (half_t)ps[1], (half_t)ps[2], (half_t)ps[3],
                           (half_t)ps[4], (half_t)ps[5], (half_t)ps[6], (half_t)ps[7] };
            P2[kk] = pv;
        }

        // PV: one conflict-free b128 g read per MFMA.
        const int lnm = ln & 7;
        #pragma unroll
        for (int kk = 0; kk < 2; kk++) {
            int gchunk = (4 * kk + quad) ^ lnm;     // 16B-chunk within 128B row
            #pragma unroll
            for (int csub = 0; csub < 16; csub++) {
                int row = csub * 16 + ln;
                half8_t a = *(const half8_t*)&g_s[(row << 6) + gchunk * 8];
                O[csub] = __builtin_amdgcn_mfma_f32_16x16x32_f16(
                              a, P2[kk], O[csub], 0, 0, 0);
            }
        }
    }

    l_run += __shfl_xor(l_run, 16);
    l_run += __shfl_xor(l_run, 32);
    float inv = 1.0f / l_run;
    // write yhT[b][q][c]: per lane fixed q=qw+ln, 16 x half4 at c=csub*16+quad*4
    half_t* yb = yhT + ((size_t)b * LEN + qw + ln) * CI;
    #pragma unroll
    for (int csub = 0; csub < 16; csub++) {
        int c = csub * 16 + quad * 4;
        half4_t v = { (half_t)(O[csub][0] * inv), (half_t)(O[csub][1] * inv),
                      (half_t)(O[csub][2] * inv), (half_t)(O[csub][3] * inv) };
        *(half4_t*)(yb + c) = v;
    }
}

// ---------------------------------------------------------------------------
// Kernel 3: MFMA zgemm. z[o,l] = sum_c wzh[o,c] yhT[l,c] + wz_b, f16 out
// into workspace; BN partial sums in f32 from un-quantized acc.
// Round-11: same granule swizzle as projmm (4-way conflict fix).
// Grid (L/128, 4, B).
// ---------------------------------------------------------------------------
__global__ __launch_bounds__(256, 2) void zmm_kernel(
    const half_t* __restrict__ yhT, const half_t* __restrict__ wzh,
    const float* __restrict__ wzb, half_t* __restrict__ zh,
    float* __restrict__ bns, float* __restrict__ bnq)
{
    __shared__ half_t ysm[128 * 32];   // y tile [l][c], 64B rows, swizzled
    __shared__ half_t wsm[128 * 32];   // W tile [o][c], 64B rows, swizzled

    const int b  = blockIdx.z;
    const int o0 = blockIdx.y * 128;
    const int l0 = blockIdx.x * 128;
    const int t  = threadIdx.x;
    const int lane = t & 63, w = t >> 6;
    const int ln = lane & 15, quad = lane >> 4;
    const int wm = w >> 1, wn = w & 1;
    const int gsw = quad ^ ((ln >> 1) & 3);    // read-side swizzled granule

    floatx4 acc[4][4];
    #pragma unroll
    for (int mi = 0; mi < 4; mi++)
        #pragma unroll
        for (int nj = 0; nj < 4; nj++) acc[mi][nj] = (floatx4)(0.0f);

    const half_t* yb = yhT + ((size_t)b * LEN + l0) * CI;
    const half_t* Wb = wzh + (size_t)o0 * CI;

    for (int k0 = 0; k0 < 256; k0 += 32) {
        __syncthreads();
        #pragma unroll
        for (int it = 0; it < 2; it++) {
            int off = t * 16 + it * 4096;
            int row = off >> 6;
            int c8s = ((off >> 4) & 3) ^ ((row >> 1) & 3);   // swizzled src col
            async16(&ysm[off >> 1], yb + (size_t)row * CI + k0 + c8s * 8);
            async16(&wsm[off >> 1], Wb + (size_t)row * CI + k0 + c8s * 8);
        }
        __syncthreads();
        half8_t af[4], bf[4];
        #pragma unroll
        for (int mi = 0; mi < 4; mi++)
            af[mi] = *(const half8_t*)&ysm[(wm * 64 + mi * 16 + ln) * 32 + gsw * 8];
        #pragma unroll
        for (int nj = 0; nj < 4; nj++)
            bf[nj] = *(const half8_t*)&wsm[(wn * 64 + nj * 16 + ln) * 32 + gsw * 8];
        #pragma unroll
        for (int mi = 0; mi < 4; mi++)
            #pragma unroll
            for (int nj = 0; nj < 4; nj++)
                acc[mi][nj] = __builtin_amdgcn_mfma_f32_16x16x32_f16(
                                  af[mi], bf[nj], acc[mi][nj], 0, 0, 0);
    }

    // C: row = l = quad*4+r, col = o = ln
    float s[4] = {0, 0, 0, 0}, s2[4] = {0, 0, 0, 0};
    #pragma unroll
    for (int nj = 0; nj < 4; nj++) {
        int o = o0 + wn * 64 + nj * 16 + ln;
        float bo = wzb[o];
        #pragma unroll
        for (int mi = 0; mi < 4; mi++) {
            int l = l0 + wm * 64 + mi * 16 + quad * 4;
            float v0 = acc[mi][nj][0] + bo, v1 = acc[mi][nj][1] + bo;
            float v2 = acc[mi][nj][2] + bo, v3 = acc[mi][nj][3] + bo;
            half4_t hv = { (half_t)v0, (half_t)v1, (half_t)v2, (half_t)v3 };
            *(half4_t*)(zh + ((size_t)b * CIN + o) * LEN + l) = hv;
            s[nj]  += (v0 + v1) + (v2 + v3);
            s2[nj] += (v0 * v0 + v1 * v1) + (v2 * v2 + v3 * v3);
        }
    }
    #pragma unroll
    for (int nj = 0; nj < 4; nj++) {
        float sv = s[nj], qv = s2[nj];
        sv += __shfl_xor(sv, 16); sv += __shfl_xor(sv, 32);
        qv += __shfl_xor(qv, 16); qv += __shfl_xor(qv, 32);
        if (quad == 0) {
            int o = o0 + wn * 64 + nj * 16 + ln;
            atomicAdd(&bns[o], sv);
            atomicAdd(&bnq[o], qv);
        }
    }
}

// ---------------------------------------------------------------------------
// Kernel 4: BN normalize (batch stats, biased var) + residual.
// Reads f16 z (half traffic), writes f32 out. 8 elements/thread.
// ---------------------------------------------------------------------------
__global__ __launch_bounds__(256) void bn_kernel(
    const half_t* __restrict__ zh, const float* __restrict__ x,
    float* __restrict__ out,
    const float* __restrict__ bns, const float* __restrict__ bnq,
    const float* __restrict__ gamma, const float* __restrict__ beta)
{
    size_t i8 = (size_t)blockIdx.x * 256 + threadIdx.x;
    size_t base = i8 << 3;
    int c = (int)((base >> 12) & (CIN - 1));
    const float invn = 1.0f / (BATCH * LEN);
    float mean = bns[c] * invn;
    float var  = bnq[c] * invn - mean * mean;
    float sc = gamma[c] * rsqrtf(var + 1e-5f);
    float sh = beta[c] - mean * sc;
    half8_t zv = *(const half8_t*)(zh + base);
    float4 x0 = *(const float4*)(x + base);
    float4 x1 = *(const float4*)(x + base + 4);
    float4 o0, o1;
    o0.x = (float)zv[0] * sc + sh + x0.x;
    o0.y = (float)zv[1] * sc + sh + x0.y;
    o0.z = (float)zv[2] * sc + sh + x0.z;
    o0.w = (float)zv[3] * sc + sh + x0.w;
    o1.x = (float)zv[4] * sc + sh + x1.x;
    o1.y = (float)zv[5] * sc + sh + x1.y;
    o1.z = (float)zv[6] * sc + sh + x1.z;
    o1.w = (float)zv[7] * sc + sh + x1.w;
    *(float4*)(out + base) = o0;
    *(float4*)(out + base + 4) = o1;
}

// ---------------------------------------------------------------------------
extern "C" void kernel_launch(void* const* d_in, const int* in_sizes, int n_in,
                              void* d_out, int out_size, void* d_ws, size_t ws_size,
                              hipStream_t stream)
{
    const float* x     = (const float*)d_in[0];
    const float* tw    = (const float*)d_in[1];
    const float* tb    = (const float*)d_in[2];
    const float* pw    = (const float*)d_in[3];
    const float* pb    = (const float*)d_in[4];
    const float* gw    = (const float*)d_in[5];
    const float* gb    = (const float*)d_in[6];
    const float* wzw   = (const float*)d_in[7];
    const float* wzb   = (const float*)d_in[8];
    const float* gamma = (const float*)d_in[9];
    const float* beta  = (const float*)d_in[10];

    float* out = (float*)d_out;

    half_t* xhT    = (half_t*)d_ws;                              // 33.6 MB
    half_t* thetaT = xhT    + (size_t)BATCH * LEN * CIN;         // 16.8 MB
    half_t* phiT   = thetaT + (size_t)BATCH * LEN * CI;          //  8.4 MB
    half_t* gH     = phiT   + (size_t)BATCH * KLEN * CI;         //  8.4 MB
    half_t* yhT    = gH     + (size_t)BATCH * CI * KLEN;         // 16.8 MB
    half_t* Wh     = yhT    + (size_t)BATCH * LEN * CI;          // 768 KB
    half_t* wzh    = Wh     + (size_t)768 * 512;                 // 256 KB
    float*  bns    = (float*)(wzh + (size_t)512 * 256);
    float*  bnq    = bns + CIN;
    // xhT region (33.6 MB) is dead after projmm -> reuse for f16 z:
    half_t* zh     = xhT;                                        // 33.6 MB

    xpose_kernel<<<dim3(65, CIN / 64, BATCH), 256, 0, stream>>>(
        x, xhT, tw, pw, gw, wzw, Wh, wzh, bns);

    projmm_kernel<<<dim3(LEN / 128, 6, BATCH), 256, 0, stream>>>(
        xhT, Wh, tb, pb, gb, thetaT, phiT, gH);

    attn_kernel<<<dim3(BATCH, LEN / 64), 256, 0, stream>>>(
        thetaT, phiT, gH, yhT);

    zmm_kernel<<<dim3(LEN / 128, CIN / 128, BATCH), 256, 0, stream>>>(
        yhT, wzh, wzb, zh, bns, bnq);

    bn_kernel<<<(BATCH * CIN * LEN) / 8 / 256, 256, 0, stream>>>(
        zh, x, out, bns, bnq, gamma, beta);
}